// Round 2
// baseline (491.732 us; speedup 1.0000x reference)
//
#include <hip/hip_runtime.h>

#define B_ 16
#define D_ 768
#define N_ 4096
#define Q_ 128

typedef __attribute__((ext_vector_type(4))) float f32x4;
typedef __attribute__((ext_vector_type(8))) short short8;
typedef __attribute__((ext_vector_type(4))) short sv4;

__device__ __forceinline__ unsigned short f2bf(float f) {
  union { float f; unsigned u; } x; x.f = f;
  unsigned u = x.u;
  unsigned r = u + 0x7fffu + ((u >> 16) & 1u);
  return (unsigned short)(r >> 16);
}

// async global->LDS 16B copy: LDS dest = uniform base + lane*16
__device__ __forceinline__ void async16(unsigned short* lds, const unsigned short* g) {
  __builtin_amdgcn_global_load_lds(
      (const __attribute__((address_space(1))) unsigned int*)g,
      (__attribute__((address_space(3))) unsigned int*)lds, 16, 0, 0);
}

// ---------------- elementwise cast fp32 -> bf16 (4/thread) ----------------
__global__ __launch_bounds__(256) void cast_bf16_kernel(
    const float* __restrict__ src, unsigned short* __restrict__ dst, int n4) {
  int i = blockIdx.x * 256 + threadIdx.x;
  if (i >= n4) return;
  float4 v = ((const float4*)src)[i];
  ushort4 o;
  o.x = f2bf(v.x); o.y = f2bf(v.y); o.z = f2bf(v.z); o.w = f2bf(v.w);
  ((ushort4*)dst)[i] = o;
}

// ---------------- transpose + cast (Wq->WqT, Wk->WkT) ----------------
__global__ __launch_bounds__(256) void transpose_cast_kernel(
    const float* __restrict__ src, unsigned short* __restrict__ dst, int rows, int cols) {
  __shared__ float tile[32][33];
  int bx = blockIdx.x * 32, by = blockIdx.y * 32;
  int tx = threadIdx.x & 31, ty = threadIdx.x >> 5;
  #pragma unroll
  for (int i = 0; i < 32; i += 8)
    tile[ty + i][tx] = src[(size_t)(by + ty + i) * cols + bx + tx];
  __syncthreads();
  #pragma unroll
  for (int i = 0; i < 32; i += 8)
    dst[(size_t)(bx + ty + i) * rows + by + tx] = f2bf(tile[tx][ty + i]);
}

// ---------------- per-row entropy of softmax (text rows), one wave/row ----------------
__global__ __launch_bounds__(256) void row_entropy_kernel(
    const float* __restrict__ X, float* __restrict__ ent, int K) {
  int row = blockIdx.x * 4 + (threadIdx.x >> 6);
  int lane = threadIdx.x & 63;
  const float* x = X + (size_t)row * K;
  float m = -__builtin_inff(), s = 0.f, t = 0.f;
  for (int k = lane; k < K; k += 64) {
    float v = x[k];
    float nm = fmaxf(m, v);
    float c = __expf(m - nm);
    float e = __expf(v - nm);
    s = s * c + e;
    t = t * c + v * e;
    m = nm;
  }
  #pragma unroll
  for (int off = 32; off > 0; off >>= 1) {
    float m2 = __shfl_xor(m, off);
    float s2 = __shfl_xor(s, off);
    float t2 = __shfl_xor(t, off);
    float nm = fmaxf(m, m2);
    float c1 = __expf(m - nm), c2 = __expf(m2 - nm);
    s = s * c1 + s2 * c2;
    t = t * c1 + t2 * c2;
    m = nm;
  }
  if (lane == 0) ent[row] = m + __logf(s) - t / s;
}

// ---------------- fused visual: entropy + transpose-cast to vfT bf16 ----------------
__global__ __launch_bounds__(256) void visual_fused_kernel(
    const float* __restrict__ vis, unsigned short* __restrict__ vfT,
    float* __restrict__ ent) {
  constexpr int LT = 72;  // 144B rows: 16B-aligned vec reads, 2-way banks
  __shared__ unsigned short tile[64 * LT];
  __shared__ float sm[256], ss[256], st[256];
  int bb = blockIdx.x >> 6;
  int n0 = (blockIdx.x & 63) * 64;
  int t = threadIdx.x, tok = t & 63, j = t >> 6;
  const float* base = vis + (size_t)bb * D_ * N_ + n0 + tok;
  unsigned short* orow = vfT + (size_t)(bb * N_ + n0) * D_;
  float m = -__builtin_inff(), s = 0.f, tt = 0.f;
  for (int dc = 0; dc < 12; dc++) {
    __syncthreads();
    #pragma unroll
    for (int i = 0; i < 16; i++) {
      int dl = j * 16 + i;
      float v = base[(size_t)(dc * 64 + dl) * N_];
      float nm = fmaxf(m, v);
      float c = __expf(m - nm), e = __expf(v - nm);
      s = s * c + e; tt = tt * c + v * e; m = nm;
      tile[tok * LT + dl] = f2bf(v);
    }
    __syncthreads();
    #pragma unroll
    for (int i2 = 0; i2 < 2; i2++) {
      int V = i2 * 256 + t;
      int r = V >> 3, cv = V & 7;
      short8 pk = *(const short8*)(tile + r * LT + cv * 8);
      *(short8*)(orow + (size_t)r * D_ + dc * 64 + cv * 8) = pk;
    }
  }
  sm[t] = m; ss[t] = s; st[t] = tt;
  __syncthreads();
  if (t < 64) {
    #pragma unroll
    for (int k = 1; k < 4; k++) {
      float m2 = sm[t + 64 * k], s2 = ss[t + 64 * k], t2 = st[t + 64 * k];
      float nm = fmaxf(m, m2);
      float c1 = __expf(m - nm), c2 = __expf(m2 - nm);
      s = s * c1 + s2 * c2; tt = tt * c1 + t2 * c2; m = nm;
    }
    ent[(size_t)bb * N_ + n0 + t] = m + __logf(s) - tt / s;
  }
}

// ---------------- softmax over 128 (te), one block/batch ----------------
__global__ __launch_bounds__(128) void softmax128_kernel(
    const float* __restrict__ ent, float* __restrict__ w) {
  int b = blockIdx.x, t = threadIdx.x;
  float v = ent[b * 128 + t];
  float m = v;
  #pragma unroll
  for (int off = 32; off; off >>= 1) m = fmaxf(m, __shfl_xor(m, off));
  __shared__ float sm2[2], ssum[2];
  int wv = t >> 6;
  if ((t & 63) == 0) sm2[wv] = m;
  __syncthreads();
  m = fmaxf(sm2[0], sm2[1]);
  float e = __expf(v - m);
  float s = e;
  #pragma unroll
  for (int off = 32; off; off >>= 1) s += __shfl_xor(s, off);
  if ((t & 63) == 0) ssum[wv] = s;
  __syncthreads();
  s = ssum[0] + ssum[1];
  w[b * 128 + t] = e / s;
}

// ---------------- softmax over 4096 (ve), one block/batch, 1024 thr ----------------
__global__ __launch_bounds__(1024) void softmax4096_kernel(
    const float* __restrict__ ent, float* __restrict__ w) {
  int b = blockIdx.x, t = threadIdx.x;
  const float* e = ent + (size_t)b * N_;
  float v[4];
  float m = -__builtin_inff();
  #pragma unroll
  for (int i = 0; i < 4; i++) { v[i] = e[t + 1024 * i]; m = fmaxf(m, v[i]); }
  #pragma unroll
  for (int off = 32; off; off >>= 1) m = fmaxf(m, __shfl_xor(m, off));
  __shared__ float red[16];
  int wv = t >> 6;
  if ((t & 63) == 0) red[wv] = m;
  __syncthreads();
  if (t < 16) {
    float x = red[t];
    #pragma unroll
    for (int off = 8; off; off >>= 1) x = fmaxf(x, __shfl_xor(x, off));
    red[t] = x;
  }
  __syncthreads();
  m = red[0];
  float ev[4];
  float s = 0.f;
  #pragma unroll
  for (int i = 0; i < 4; i++) { ev[i] = __expf(v[i] - m); s += ev[i]; }
  #pragma unroll
  for (int off = 32; off; off >>= 1) s += __shfl_xor(s, off);
  __syncthreads();
  if ((t & 63) == 0) red[wv] = s;
  __syncthreads();
  if (t < 16) {
    float x = red[t];
    #pragma unroll
    for (int off = 8; off; off >>= 1) x += __shfl_xor(x, off);
    red[t] = x;
  }
  __syncthreads();
  s = red[0];
  #pragma unroll
  for (int i = 0; i < 4; i++) w[(size_t)b * N_ + t + 1024 * i] = ev[i] / s;
}

// ---------------- bf16 NT GEMM: C[m,n] = sum_k A[m,k]*B[n,k] (+bias) ----------------
// MODE 0: plain store [M][768]; MODE 1: +bias; MODE 2: +bias, store vT[b][n][q]
template <int MODE>
__global__ __launch_bounds__(256) void gemm_nt_kernel(
    const unsigned short* __restrict__ A, const unsigned short* __restrict__ Bm,
    const float* __restrict__ bias, unsigned short* __restrict__ C) {
  constexpr int LDA = 40;
  __shared__ unsigned short As[64 * LDA];
  __shared__ unsigned short Bs[64 * LDA];
  int m0 = blockIdx.x * 64, n0 = blockIdx.y * 64;
  int t = threadIdx.x, wave = t >> 6, lane = t & 63;
  int wm = (wave & 1) * 32, wn = (wave >> 1) * 32;
  int fl = lane & 15, fq = lane >> 4;
  f32x4 acc[2][2];
  #pragma unroll
  for (int i = 0; i < 2; i++)
    #pragma unroll
    for (int j = 0; j < 2; j++) acc[i][j] = {0.f, 0.f, 0.f, 0.f};
  int sr = t >> 2, sc = (t & 3) * 8;
  for (int k0 = 0; k0 < D_; k0 += 32) {
    uint4 av = *(const uint4*)(A + (size_t)(m0 + sr) * D_ + k0 + sc);
    uint4 bv = *(const uint4*)(Bm + (size_t)(n0 + sr) * D_ + k0 + sc);
    __syncthreads();
    *(uint4*)(As + sr * LDA + sc) = av;
    *(uint4*)(Bs + sr * LDA + sc) = bv;
    __syncthreads();
    short8 afr[2], bfr[2];
    #pragma unroll
    for (int i = 0; i < 2; i++)
      afr[i] = *(const short8*)(As + (wm + i * 16 + fl) * LDA + fq * 8);
    #pragma unroll
    for (int j = 0; j < 2; j++)
      bfr[j] = *(const short8*)(Bs + (wn + j * 16 + fl) * LDA + fq * 8);
    #pragma unroll
    for (int i = 0; i < 2; i++)
      #pragma unroll
      for (int j = 0; j < 2; j++)
        acc[i][j] = __builtin_amdgcn_mfma_f32_16x16x32_bf16(afr[i], bfr[j], acc[i][j], 0, 0, 0);
  }
  #pragma unroll
  for (int i = 0; i < 2; i++)
    #pragma unroll
    for (int j = 0; j < 2; j++) {
      int n = n0 + wn + j * 16 + fl;
      float bb = (MODE >= 1) ? bias[n] : 0.f;
      #pragma unroll
      for (int r = 0; r < 4; r++) {
        int m = m0 + wm + i * 16 + fq * 4 + r;
        float val = acc[i][j][r] + bb;
        if (MODE == 2) {
          int bt = m >> 7, q = m & 127;
          C[((size_t)bt * D_ + n) * Q_ + q] = f2bf(val);
        } else {
          C[(size_t)m * D_ + n] = f2bf(val);
        }
      }
    }
}

// ---------------- u = Wk^T bq, bw = Wq^T bk, c0 = bq.bk ----------------
__global__ __launch_bounds__(256) void ubw_kernel(
    const float* __restrict__ Wk, const float* __restrict__ Wq,
    const float* __restrict__ bq, const float* __restrict__ bk,
    float* __restrict__ u, float* __restrict__ bw, float* __restrict__ c0) {
  int blk = blockIdx.x;
  int t = threadIdx.x;
  if (blk == 24) {
    float s = 0.f;
    for (int d = t; d < D_; d += 256) s += bq[d] * bk[d];
    #pragma unroll
    for (int off = 32; off; off >>= 1) s += __shfl_xor(s, off);
    __shared__ float r4[4];
    if ((t & 63) == 0) r4[t >> 6] = s;
    __syncthreads();
    if (t == 0) c0[0] = r4[0] + r4[1] + r4[2] + r4[3];
    return;
  }
  const float* W = (blk < 12) ? Wk : Wq;
  const float* bvv = (blk < 12) ? bq : bk;
  float* outp = (blk < 12) ? u : bw;
  int e0 = (blk % 12) * 64;
  int e = e0 + (t & 63), j = t >> 6;
  float s = 0.f;
  for (int d = j * 192; d < j * 192 + 192; d++)
    s += W[(size_t)d * D_ + e] * bvv[d];
  __shared__ float acc4[4][64];
  acc4[j][t & 63] = s;
  __syncthreads();
  if (t < 64) outp[e0 + t] = acc4[0][t] + acc4[1][t] + acc4[2][t] + acc4[3][t];
}

// ---------------- skq[q] = text[q,:].u + c0 ----------------
__global__ __launch_bounds__(256) void skq_kernel(
    const float* __restrict__ text, const float* __restrict__ u,
    const float* __restrict__ c0, float* __restrict__ skq) {
  int row = blockIdx.x * 4 + (threadIdx.x >> 6);
  int lane = threadIdx.x & 63;
  const float* x = text + (size_t)row * D_;
  float s = 0.f;
  for (int e = lane; e < D_; e += 64) s += x[e] * u[e];
  #pragma unroll
  for (int off = 32; off; off >>= 1) s += __shfl_xor(s, off);
  if (lane == 0) skq[row] = s + c0[0];
}

// ---------------- fused attention main kernel ----------------
// per block: 128 tokens x full Q=128. S = vfT*kq^T, softmax w/ ve*te modulation, O^T = vT*P^T
__global__ __launch_bounds__(256, 2) void attn_main_kernel(
    const unsigned short* __restrict__ vfT,  // [B][N][768] bf16
    const unsigned short* __restrict__ kq,   // [B][Q][768] bf16
    const unsigned short* __restrict__ vT,   // [B][768][Q] bf16
    const float* __restrict__ ve,            // [B][4096]
    const float* __restrict__ te,            // [B][128]
    const float* __restrict__ skq,           // [B*Q]
    float* __restrict__ out)                 // [B][768][4096]
{
  constexpr int LP = 136;  // P and V strides: 272B rows
  // phase A: As[128*64] | Bs[128*64] (no pad: glb_lds dest, XOR-swizzled source)
  // phase B: Ps[128*136] | Vs[96*136]
  __shared__ unsigned short region0[30464];       // 60928 B
  __shared__ float stats[2][128][2];
  unsigned short* As = region0;                   // elems [0, 8192)
  unsigned short* Bs = region0 + 8192;            // elems [8192, 16384)
  unsigned short* Ps = region0;                   // elems [0, 17408)
  unsigned short* Vs = region0 + 17408;           // elems [17408, 30464)

  const int bb = blockIdx.x >> 5;
  const int n0 = (blockIdx.x & 31) * 128;
  const int t = threadIdx.x;
  const int wave = t >> 6, lane = t & 63;
  const int fl = lane & 15, fq = lane >> 4;
  const int wm = (wave & 1) * 64;   // token half (phase A)
  const int wq = (wave >> 1) * 64;  // q half (phase A)

  // staging source pointers (XOR granule swizzle on source; LDS stays linear)
  const int rsub = lane >> 3;                 // row within 8-row chunk
  const int gsw = (lane & 7) ^ rsub;          // swizzled 16B-granule index
  const unsigned short* gA = vfT + (size_t)(bb * N_ + n0 + rsub) * D_ + gsw * 8;
  const unsigned short* gB = kq + (size_t)(bb * Q_ + rsub) * D_ + gsw * 8;

  f32x4 acc[4][4];
  #pragma unroll
  for (int i = 0; i < 4; i++)
    #pragma unroll
    for (int j = 0; j < 4; j++) acc[i][j] = {0.f, 0.f, 0.f, 0.f};

  // ---------- phase A: S = vfT * kq^T ----------
  for (int k0 = 0; k0 < D_; k0 += 64) {
    __syncthreads();
    #pragma unroll
    for (int i = 0; i < 4; i++) {
      const int I = wave * 4 + i;               // 8-row chunk index 0..15
      async16(As + I * 512, gA + (size_t)I * 8 * D_ + k0);
      async16(Bs + I * 512, gB + (size_t)I * 8 * D_ + k0);
    }
    __syncthreads();  // drains vmcnt before ds_read
    #pragma unroll
    for (int ks = 0; ks < 2; ks++) {
      short8 afr[4], bfr[4];
      const int p = ((ks * 4 + fq) ^ (fl & 7)) * 8;   // de-swizzled granule
      #pragma unroll
      for (int i = 0; i < 4; i++)
        afr[i] = *(const short8*)(As + (wm + i * 16 + fl) * 64 + p);
      #pragma unroll
      for (int j = 0; j < 4; j++)
        bfr[j] = *(const short8*)(Bs + (wq + j * 16 + fl) * 64 + p);
      #pragma unroll
      for (int i = 0; i < 4; i++)
        #pragma unroll
        for (int j = 0; j < 4; j++)
          acc[i][j] = __builtin_amdgcn_mfma_f32_16x16x32_bf16(afr[i], bfr[j], acc[i][j], 0, 0, 0);
    }
  }

  // ---------- softmax with entropy modulation ----------
  const float rsD = 0.03608439182435161f;  // 1/sqrt(768)
  float tev[4], skv[4];
  #pragma unroll
  for (int j = 0; j < 4; j++) {
    int q = wq + j * 16 + fl;
    tev[j] = te[bb * Q_ + q];
    skv[j] = skq[bb * Q_ + q];
  }
  float vev4[4][4];
  #pragma unroll
  for (int i = 0; i < 4; i++)
    #pragma unroll
    for (int r = 0; r < 4; r++)
      vev4[i][r] = ve[(size_t)bb * N_ + n0 + wm + i * 16 + fq * 4 + r];

  float rmax[4][4], rsum[4][4];
  #pragma unroll
  for (int i = 0; i < 4; i++)
    #pragma unroll
    for (int r = 0; r < 4; r++) rmax[i][r] = -__builtin_inff();
  #pragma unroll
  for (int i = 0; i < 4; i++)
    #pragma unroll
    for (int j = 0; j < 4; j++)
      #pragma unroll
      for (int r = 0; r < 4; r++) {
        float L = (acc[i][j][r] + skv[j]) * rsD * vev4[i][r] * tev[j];
        acc[i][j][r] = L;
        rmax[i][r] = fmaxf(rmax[i][r], L);
      }
  #pragma unroll
  for (int off = 1; off < 16; off <<= 1)
    #pragma unroll
    for (int i = 0; i < 4; i++)
      #pragma unroll
      for (int r = 0; r < 4; r++)
        rmax[i][r] = fmaxf(rmax[i][r], __shfl_xor(rmax[i][r], off));
  #pragma unroll
  for (int i = 0; i < 4; i++)
    #pragma unroll
    for (int r = 0; r < 4; r++) rsum[i][r] = 0.f;
  #pragma unroll
  for (int i = 0; i < 4; i++)
    #pragma unroll
    for (int j = 0; j < 4; j++)
      #pragma unroll
      for (int r = 0; r < 4; r++) {
        float e = __expf(acc[i][j][r] - rmax[i][r]);
        acc[i][j][r] = e;
        rsum[i][r] += e;
      }
  #pragma unroll
  for (int off = 1; off < 16; off <<= 1)
    #pragma unroll
    for (int i = 0; i < 4; i++)
      #pragma unroll
      for (int r = 0; r < 4; r++) rsum[i][r] += __shfl_xor(rsum[i][r], off);

  const int qh = wq >> 6;
  if (fl == 0) {
    #pragma unroll
    for (int i = 0; i < 4; i++)
      #pragma unroll
      for (int r = 0; r < 4; r++) {
        int m = wm + i * 16 + fq * 4 + r;
        stats[qh][m][0] = rmax[i][r];
        stats[qh][m][1] = rsum[i][r];
      }
  }
  __syncthreads();  // all As/Bs frag reads done before Ps overwrite
  float fac[4][4];
  #pragma unroll
  for (int i = 0; i < 4; i++)
    #pragma unroll
    for (int r = 0; r < 4; r++) {
      int m = wm + i * 16 + fq * 4 + r;
      float M2 = stats[1 - qh][m][0], S2 = stats[1 - qh][m][1];
      float Mf = fmaxf(rmax[i][r], M2);
      float sf = rsum[i][r] * __expf(rmax[i][r] - Mf) + S2 * __expf(M2 - Mf);
      fac[i][r] = __expf(rmax[i][r] - Mf) / sf;
    }
  #pragma unroll
  for (int i = 0; i < 4; i++)
    #pragma unroll
    for (int j = 0; j < 4; j++)
      #pragma unroll
      for (int r = 0; r < 4; r++) {
        int m = wm + i * 16 + fq * 4 + r;
        int q = wq + j * 16 + fl;
        Ps[m * LP + q] = f2bf(acc[i][j][r] * fac[i][r]);
      }

  // ---------- phase B: O^T = vT * P^T, d-chunks of 96 ----------
  const int wd = (wave & 1) * 48;   // d half within chunk
  const int wm2 = (wave >> 1) * 64; // token half
  for (int dc = 0; dc < 8; dc++) {
    __syncthreads();  // covers Ps writes (dc=0) and prior-chunk Vs reads
    const unsigned short* vbase = vT + ((size_t)bb * D_ + dc * 96) * Q_;
    #pragma unroll
    for (int i = 0; i < 6; i++) {
      const int c = t + 256 * i;
      const int d = c >> 4, qc = (c & 15) * 8;
      const uint4 v = *(const uint4*)(vbase + (size_t)d * Q_ + qc);
      *(uint4*)(Vs + d * LP + qc) = v;
    }
    __syncthreads();
    f32x4 acc2[3][4];
    #pragma unroll
    for (int i = 0; i < 3; i++)
      #pragma unroll
      for (int j = 0; j < 4; j++) acc2[i][j] = {0.f, 0.f, 0.f, 0.f};
    #pragma unroll
    for (int ks = 0; ks < 4; ks++) {
      short8 vfr[3], pfr[4];
      #pragma unroll
      for (int i = 0; i < 3; i++)
        vfr[i] = *(const short8*)(Vs + (wd + i * 16 + fl) * LP + ks * 32 + fq * 8);
      #pragma unroll
      for (int j = 0; j < 4; j++)
        pfr[j] = *(const short8*)(Ps + (wm2 + j * 16 + fl) * LP + ks * 32 + fq * 8);
      #pragma unroll
      for (int i = 0; i < 3; i++)
        #pragma unroll
        for (int j = 0; j < 4; j++)
          acc2[i][j] = __builtin_amdgcn_mfma_f32_16x16x32_bf16(vfr[i], pfr[j], acc2[i][j], 0, 0, 0);
    }
    float* obase = out + ((size_t)bb * D_ + dc * 96) * N_ + n0;
    #pragma unroll
    for (int i = 0; i < 3; i++)
      #pragma unroll
      for (int j = 0; j < 4; j++) {
        int mm = wm2 + j * 16 + fl;
        #pragma unroll
        for (int r = 0; r < 4; r++) {
          int d = wd + i * 16 + fq * 4 + r;
          obase[(size_t)d * N_ + mm] = acc2[i][j][r];
        }
      }
  }
}

extern "C" void kernel_launch(void* const* d_in, const int* in_sizes, int n_in,
                              void* d_out, int out_size, void* d_ws, size_t ws_size,
                              hipStream_t stream) {
  const float* vis  = (const float*)d_in[0];
  const float* text = (const float*)d_in[1];
  const float* Wq   = (const float*)d_in[2];
  const float* bq   = (const float*)d_in[3];
  const float* Wk   = (const float*)d_in[4];
  const float* bk   = (const float*)d_in[5];
  const float* Wv   = (const float*)d_in[6];
  const float* bv   = (const float*)d_in[7];
  float* out = (float*)d_out;
  char* ws = (char*)d_ws;

  unsigned short* textb = (unsigned short*)(ws + 0);          // 3,145,728
  unsigned short* Wvb   = (unsigned short*)(ws + 3145728);    // 1,179,648
  unsigned short* WqTb  = (unsigned short*)(ws + 4325376);    // 1,179,648
  unsigned short* WkTb  = (unsigned short*)(ws + 5505024);    // 1,179,648
  unsigned short* Wx    = (unsigned short*)(ws + 6684672);    // 1,179,648
  unsigned short* kqb   = (unsigned short*)(ws + 7864320);    // 3,145,728
  unsigned short* vTb   = (unsigned short*)(ws + 11010048);   // 3,145,728
  unsigned short* vfTb  = (unsigned short*)(ws + 14155776);   // 100,663,296
  float* ent_t = (float*)(ws + 114819072);                    // 8,192
  float* tew   = (float*)(ws + 114827264);                    // 8,192
  float* ent_v = (float*)(ws + 114835456);                    // 262,144
  float* vew   = (float*)(ws + 115097600);                    // 262,144
  float* skqv  = (float*)(ws + 115359744);                    // 8,192
  float* u     = (float*)(ws + 115367936);                    // 3,072
  float* bw    = (float*)(ws + 115371008);                    // 3,072
  float* c0    = (float*)(ws + 115374080);                    // 64
  // total ws: ~115.4 MB (ws is 768 MB per harness poison fills)

  cast_bf16_kernel<<<1536, 256, 0, stream>>>(text, textb, 2048 * 768 / 4);
  cast_bf16_kernel<<<576, 256, 0, stream>>>(Wv, Wvb, 768 * 768 / 4);
  transpose_cast_kernel<<<dim3(24, 24), 256, 0, stream>>>(Wq, WqTb, 768, 768);
  transpose_cast_kernel<<<dim3(24, 24), 256, 0, stream>>>(Wk, WkTb, 768, 768);

  // Wx[e2][e1] = sum_d Wq[d,e2] Wk[d,e1]
  gemm_nt_kernel<0><<<dim3(12, 12), 256, 0, stream>>>(WqTb, WkTb, nullptr, Wx);
  ubw_kernel<<<25, 256, 0, stream>>>(Wk, Wq, bq, bk, u, bw, c0);

  // kq = text @ Wx^T + bw ; vT = (text @ Wv^T + bv)^T
  gemm_nt_kernel<1><<<dim3(32, 12), 256, 0, stream>>>(textb, Wx, bw, kqb);
  gemm_nt_kernel<2><<<dim3(32, 12), 256, 0, stream>>>(textb, Wvb, bv, vTb);
  skq_kernel<<<512, 256, 0, stream>>>(text, u, c0, skqv);

  row_entropy_kernel<<<512, 256, 0, stream>>>(text, ent_t, 768);
  softmax128_kernel<<<16, 128, 0, stream>>>(ent_t, tew);
  visual_fused_kernel<<<1024, 256, 0, stream>>>(vis, vfTb, ent_v);
  softmax4096_kernel<<<16, 1024, 0, stream>>>(ent_v, vew);

  attn_main_kernel<<<512, 256, 0, stream>>>(vfTb, kqb, vTb, vew, tew, skqv, out);
}